// Round 19
// baseline (270.724 us; speedup 1.0000x reference)
//
#include <hip/hip_runtime.h>
#include <hip/hip_bf16.h>
#include <stdint.h>

typedef unsigned short u16;
typedef __bf16 bf16x8 __attribute__((ext_vector_type(8)));
typedef float f32x4 __attribute__((ext_vector_type(4)));
typedef unsigned short u16x8 __attribute__((ext_vector_type(8)));

#define QEPS 1e-8f

__device__ __forceinline__ u16 f32_to_bf16_rne(float f) {
    uint32_t u = __float_as_uint(f);
    u += 0x7fffu + ((u >> 16) & 1u);
    return (u16)(u >> 16);
}

// -------- merged prep (grid-stride, G11): x f32->bf16 | w dequant->bf16 --------
__global__ void prep_bf16(const float* __restrict__ x, const float* __restrict__ w,
                          const float* __restrict__ ss, u16* __restrict__ xb,
                          u16* __restrict__ wb, int n8x, int n8w, int N, int K) {
    const int stride = gridDim.x * blockDim.x;
    const int tot = n8x + n8w;
    for (int idx = blockIdx.x * blockDim.x + threadIdx.x; idx < tot; idx += stride) {
        if (idx < n8x) {
            const float4* p = (const float4*)(x + (size_t)idx * 8);
            float4 a = p[0], b = p[1];
            u16x8 r;
            r[0] = f32_to_bf16_rne(a.x); r[1] = f32_to_bf16_rne(a.y);
            r[2] = f32_to_bf16_rne(a.z); r[3] = f32_to_bf16_rne(a.w);
            r[4] = f32_to_bf16_rne(b.x); r[5] = f32_to_bf16_rne(b.y);
            r[6] = f32_to_bf16_rne(b.z); r[7] = f32_to_bf16_rne(b.w);
            *(u16x8*)(xb + (size_t)idx * 8) = r;
        } else {
            int wi = idx - n8x;
            int pr = K >> 3;
            int n = wi / pr;
            int k8 = (wi - n * pr) << 3;
            float s = ss[(size_t)(k8 >> 7) * N + n] + QEPS;   // 8 k never straddle a group
            const float4* p = (const float4*)(w + (size_t)n * K + k8);
            float4 a = p[0], b = p[1];
            float v[8] = {a.x, a.y, a.z, a.w, b.x, b.y, b.z, b.w};
            u16x8 r;
#pragma unroll
            for (int i = 0; i < 8; ++i) {
                float q = rintf(v[i] / s);    // IEEE f32 div + RNE == jnp f32 semantics
                r[i] = f32_to_bf16_rne(q * s);
            }
            *(u16x8*)(wb + (size_t)n * K + k8) = r;
        }
    }
}

// ======================= 256x256 pipelined bf16 GEMM (R13) =======================
// Ring-4 x BK=32 slabs, lookahead-3. End-of-slab vmcnt(4) confirms tiles t+1
// AND t+2 (sealed by the barrier for every wave) -> next slab's fragment reads
// of tile t+2 may be woven mid-slab. Fine stage spread (m196): the 4
// global_load_lds of STAGE(t+3) issued one-per-MROW at rows 0,1,2,3.
// One counted vmcnt + one barrier per slab. setprio removed (m190 A/B).
#define BM 256
#define BN 256
#define SLOTB 32768     // bytes per ring slot: A 16K + B 16K
#define ABYT 16384
#define LDSB 131072

#define ASYNC16(g, l)                                                                      \
    __builtin_amdgcn_global_load_lds((const __attribute__((address_space(1))) void*)(g),   \
                                     (__attribute__((address_space(3))) void*)(l), 16, 0, 0)
#define VMCNT(n) asm volatile("s_waitcnt vmcnt(" #n ")" ::: "memory")
#define BAR()    __builtin_amdgcn_s_barrier()
#define MFMA(a, b, c) __builtin_amdgcn_mfma_f32_16x16x32_bf16((a), (b), (c), 0, 0, 0)

__global__ __launch_bounds__(512, 2) void gemm_bf16_bt_256(
        const u16* __restrict__ A,    // [M][K] bf16
        const u16* __restrict__ B,    // [N][K] bf16
        const float* __restrict__ bias,
        float* __restrict__ C,        // [M][N] f32
        int M, int N, int K) {
    extern __shared__ char lds[];
    const int tid  = threadIdx.x;
    const int wave = tid >> 6;
    const int lane = tid & 63;

    // XCD-aware bijective swizzle (grid 512, %8==0)
    const int nwg = gridDim.x;
    const int cpx = nwg >> 3;
    const int bid = blockIdx.x;
    const int swz = (bid & 7) * cpx + (bid >> 3);
    const int nbn = N / BN;
    const int bm  = swz / nbn;
    const int bn  = swz - bm * nbn;

    const int wr = wave >> 2;                // 0..1 -> 128-row band
    const int wc = wave & 3;                 // 0..3 -> 64-col band

    // staging sources (k pre-swizzled: kb ^= ((row>>1)&3)<<4, involution in 64-B row)
    const int srow  = tid >> 2;                                        // 0..127
    const int kbsrc = ((tid & 3) << 4) ^ (((tid >> 3) & 3) << 4);
    const char* gA0 = (const char*)A + ((size_t)(bm * BM + srow) * K) * 2 + kbsrc;
    const char* gA1 = (const char*)A + ((size_t)(bm * BM + 128 + srow) * K) * 2 + kbsrc;
    const char* gB0 = (const char*)B + ((size_t)(bn * BN + srow) * K) * 2 + kbsrc;
    const char* gB1 = (const char*)B + ((size_t)(bn * BN + 128 + srow) * K) * 2 + kbsrc;

    // one quarter of a slab's staging
    auto STG = [&](int t, int part) {
        const size_t ko = (size_t)t << 6;               // t * 32k * 2B
        char* d = lds + ((t & 3) * SLOTB) + (wave << 10);
        if (part == 0)      ASYNC16(gA0 + ko, d);
        else if (part == 1) ASYNC16(gA1 + ko, d + 8192);
        else if (part == 2) ASYNC16(gB0 + ko, d + ABYT);
        else                ASYNC16(gB1 + ko, d + ABYT + 8192);
    };

    // fragment read bases (same XOR on read address)
    const int kx = ((lane >> 4) ^ ((lane >> 1) & 3)) << 4;
    const char* pa = lds + (size_t)(wr * 128 + (lane & 15)) * 64 + kx;
    const char* pb = lds + ABYT + (size_t)(wc * 64 + (lane & 15)) * 64 + kx;

    f32x4 acc[8][4] = {};
    bf16x8 aX[8], bX[4], aY[8], bY[4];

#define RD_B(DST, i) DST[i] = *(const bf16x8*)(pb + bon + (i) * 1024)
#define RD_A(DST, i) DST[i] = *(const bf16x8*)(pa + bon + (i) * 1024)
#define MROW(CA, CB, m)                                                       \
    acc[m][0] = MFMA(CA[m], CB[0], acc[m][0]);                                \
    acc[m][1] = MFMA(CA[m], CB[1], acc[m][1]);                                \
    acc[m][2] = MFMA(CA[m], CB[2], acc[m][2]);                                \
    acc[m][3] = MFMA(CA[m], CB[3], acc[m][3]);

    // slab t (R13-verified): compute (CA,CB); weave next-slab reads into
    // (NA,NB); stage quarters of slab t+3 after MROWs 0,1,2,3.
#define SLAB(CA, CB, NA, NB, t, DO_STAGE, DO_NEXT, VMSTMT)                    \
    {                                                                         \
        const int bon = (((t) + 1) & 3) * SLOTB;                              \
        MROW(CA, CB, 0)                                                       \
        if (DO_NEXT) { RD_B(NB, 0); RD_B(NB, 1); }                            \
        if (DO_STAGE) STG((t) + 3, 0);                                        \
        MROW(CA, CB, 1)                                                       \
        if (DO_NEXT) { RD_B(NB, 2); RD_B(NB, 3); }                            \
        if (DO_STAGE) STG((t) + 3, 1);                                        \
        MROW(CA, CB, 2)                                                       \
        if (DO_NEXT) { RD_A(NA, 0); RD_A(NA, 1); }                            \
        if (DO_STAGE) STG((t) + 3, 2);                                        \
        MROW(CA, CB, 3)                                                       \
        if (DO_NEXT) { RD_A(NA, 2); RD_A(NA, 3); }                            \
        if (DO_STAGE) STG((t) + 3, 3);                                        \
        MROW(CA, CB, 4)                                                       \
        if (DO_NEXT) { RD_A(NA, 4); RD_A(NA, 5); }                            \
        MROW(CA, CB, 5)                                                       \
        if (DO_NEXT) { RD_A(NA, 6); RD_A(NA, 7); }                            \
        MROW(CA, CB, 6)                                                       \
        MROW(CA, CB, 7)                                                       \
        VMSTMT;                                                               \
        BAR();                                                                \
    }

    const int NT = K >> 5;                   // 128 slabs of 32 k

    // prologue: stage 0,1,2; vmcnt(4) confirms tiles 0 AND 1 (sealed by the
    // barrier for all waves); then load slab-0 fragments into set X.
    STG(0, 0); STG(0, 1); STG(0, 2); STG(0, 3);
    STG(1, 0); STG(1, 1); STG(1, 2); STG(1, 3);
    STG(2, 0); STG(2, 1); STG(2, 2); STG(2, 3);
    VMCNT(4);
    BAR();
    {
        const int bon = 0;
#pragma unroll
        for (int n = 0; n < 4; ++n) RD_B(bX, n);
#pragma unroll
        for (int m = 0; m < 8; ++m) RD_A(aX, m);
    }

    // steady: end-of-slab vmcnt(4) leaves only tile t+3 outstanding ->
    // confirms t+1 (next compute) and t+2 (next slab's woven prefetch).
    for (int t = 0; t < NT - 4; t += 2) {
        SLAB(aX, bX, aY, bY, t,     true, true, VMCNT(4))
        SLAB(aY, bY, aX, bX, t + 1, true, true, VMCNT(4))
    }
    SLAB(aX, bX, aY, bY, NT - 4, true,  true,  VMCNT(4))   // stages NT-1; confirms NT-3,NT-2
    SLAB(aY, bY, aX, bX, NT - 3, false, true,  VMCNT(0))   // confirms NT-1
    SLAB(aX, bX, aY, bY, NT - 2, false, true,  (void)0)
    SLAB(aY, bY, aX, bX, NT - 1, false, false, (void)0)

    // ---- epilogue: C/D layout row=(lane>>4)*4+i, col=lane&15 ----
    const int r0 = bm * BM + wr * 128 + ((lane >> 4) << 2);
    const int c0 = bn * BN + wc * 64 + (lane & 15);
    float bv[4];
#pragma unroll
    for (int n = 0; n < 4; ++n) bv[n] = bias[c0 + n * 16];
#pragma unroll
    for (int m = 0; m < 8; ++m)
#pragma unroll
        for (int n = 0; n < 4; ++n)
#pragma unroll
            for (int i = 0; i < 4; ++i)
                C[(size_t)(r0 + (m << 4) + i) * N + (c0 + (n << 4))] = acc[m][n][i] + bv[n];
}

extern "C" void kernel_launch(void* const* d_in, const int* in_sizes, int n_in,
                              void* d_out, int out_size, void* d_ws, size_t ws_size,
                              hipStream_t stream) {
    const float* x    = (const float*)d_in[0];   // [B,S,K] f32
    const float* w    = (const float*)d_in[1];   // [N,K]   f32
    const float* bias = (const float*)d_in[2];   // [N]     f32
    const float* ss   = (const float*)d_in[3];   // [K/128, N] f32
    float* out        = (float*)d_out;           // [B,S,N] f32

    const int N = in_sizes[2];            // 4096
    const int K = in_sizes[1] / N;        // 4096
    const int M = in_sizes[0] / K;        // 8192

    u16* xb = (u16*)d_ws;                        // [M][K] bf16
    u16* wb = xb + (size_t)M * K;                // [N][K] bf16

    int n8x = (M * K) >> 3;
    int n8w = (N * K) >> 3;
    prep_bf16<<<2048, 256, 0, stream>>>(x, w, ss, xb, wb, n8x, n8w, N, K);

    (void)hipFuncSetAttribute((const void*)gemm_bf16_bt_256,
                              hipFuncAttributeMaxDynamicSharedMemorySize, LDSB);
    dim3 grid((M / BM) * (N / BN));              // 32*16 = 512, %8 == 0
    gemm_bf16_bt_256<<<grid, 512, LDSB, stream>>>(xb, wb, bias, out, M, N, K);
}

// Round 20
// 261.841 us; speedup vs baseline: 1.0339x; 1.0339x over previous
//
#include <hip/hip_runtime.h>
#include <hip/hip_bf16.h>
#include <stdint.h>

typedef unsigned short u16;
typedef __bf16 bf16x8 __attribute__((ext_vector_type(8)));
typedef float f32x4 __attribute__((ext_vector_type(4)));
typedef unsigned short u16x8 __attribute__((ext_vector_type(8)));

#define QEPS 1e-8f

__device__ __forceinline__ u16 f32_to_bf16_rne(float f) {
    uint32_t u = __float_as_uint(f);
    u += 0x7fffu + ((u >> 16) & 1u);
    return (u16)(u >> 16);
}

// -------- merged prep: x f32->bf16 [M][K]  |  w dequant->bf16 [N][K] --------
__global__ void prep_bf16(const float* __restrict__ x, const float* __restrict__ w,
                          const float* __restrict__ ss, u16* __restrict__ xb,
                          u16* __restrict__ wb, int n8x, int n8w, int N, int K) {
    int idx = blockIdx.x * blockDim.x + threadIdx.x;
    if (idx < n8x) {
        const float4* p = (const float4*)(x + (size_t)idx * 8);
        float4 a = p[0], b = p[1];
        u16x8 r;
        r[0] = f32_to_bf16_rne(a.x); r[1] = f32_to_bf16_rne(a.y);
        r[2] = f32_to_bf16_rne(a.z); r[3] = f32_to_bf16_rne(a.w);
        r[4] = f32_to_bf16_rne(b.x); r[5] = f32_to_bf16_rne(b.y);
        r[6] = f32_to_bf16_rne(b.z); r[7] = f32_to_bf16_rne(b.w);
        *(u16x8*)(xb + (size_t)idx * 8) = r;
    } else {
        int wi = idx - n8x;
        if (wi >= n8w) return;
        int pr = K >> 3;
        int n = wi / pr;
        int k8 = (wi - n * pr) << 3;
        float s = ss[(size_t)(k8 >> 7) * N + n] + QEPS;   // 8 k never straddle a 128-group
        const float4* p = (const float4*)(w + (size_t)n * K + k8);
        float4 a = p[0], b = p[1];
        float v[8] = {a.x, a.y, a.z, a.w, b.x, b.y, b.z, b.w};
        u16x8 r;
#pragma unroll
        for (int i = 0; i < 8; ++i) {
            float q = rintf(v[i] / s);    // IEEE f32 div + RNE == jnp f32 semantics
            r[i] = f32_to_bf16_rne(q * s);
        }
        *(u16x8*)(wb + (size_t)n * K + k8) = r;
    }
}

// ======================= 256x256 pipelined bf16 GEMM (R13/R18) =======================
// Ring-4 x BK=32 slabs, lookahead-3. End-of-slab vmcnt(4) confirms tiles t+1
// AND t+2 (sealed by the barrier for every wave) -> next slab's fragment reads
// of tile t+2 may be woven mid-slab (cross-slab register double-buffer, R9).
// Fine stage spread (m196/R13): the 4 global_load_lds of STAGE(t+3) issued
// one-per-MROW at rows 0,1,2,3. One counted vmcnt + one barrier per slab.
// setprio(1) around MFMA clusters (R19 A/B: removing it cost ~2%).
#define BM 256
#define BN 256
#define SLOTB 32768     // bytes per ring slot: A 16K + B 16K
#define ABYT 16384
#define LDSB 131072

#define ASYNC16(g, l)                                                                      \
    __builtin_amdgcn_global_load_lds((const __attribute__((address_space(1))) void*)(g),   \
                                     (__attribute__((address_space(3))) void*)(l), 16, 0, 0)
#define VMCNT(n) asm volatile("s_waitcnt vmcnt(" #n ")" ::: "memory")
#define BAR()    __builtin_amdgcn_s_barrier()
#define MFMA(a, b, c) __builtin_amdgcn_mfma_f32_16x16x32_bf16((a), (b), (c), 0, 0, 0)

__global__ __launch_bounds__(512, 2) void gemm_bf16_bt_256(
        const u16* __restrict__ A,    // [M][K] bf16
        const u16* __restrict__ B,    // [N][K] bf16
        const float* __restrict__ bias,
        float* __restrict__ C,        // [M][N] f32
        int M, int N, int K) {
    extern __shared__ char lds[];
    const int tid  = threadIdx.x;
    const int wave = tid >> 6;
    const int lane = tid & 63;

    // XCD-aware bijective swizzle (grid 512, %8==0)
    const int nwg = gridDim.x;
    const int cpx = nwg >> 3;
    const int bid = blockIdx.x;
    const int swz = (bid & 7) * cpx + (bid >> 3);
    const int nbn = N / BN;
    const int bm  = swz / nbn;
    const int bn  = swz - bm * nbn;

    const int wr = wave >> 2;                // 0..1 -> 128-row band
    const int wc = wave & 3;                 // 0..3 -> 64-col band

    // staging sources (k pre-swizzled: kb ^= ((row>>1)&3)<<4, involution in 64-B row)
    const int srow  = tid >> 2;                                        // 0..127
    const int kbsrc = ((tid & 3) << 4) ^ (((tid >> 3) & 3) << 4);
    const char* gA0 = (const char*)A + ((size_t)(bm * BM + srow) * K) * 2 + kbsrc;
    const char* gA1 = (const char*)A + ((size_t)(bm * BM + 128 + srow) * K) * 2 + kbsrc;
    const char* gB0 = (const char*)B + ((size_t)(bn * BN + srow) * K) * 2 + kbsrc;
    const char* gB1 = (const char*)B + ((size_t)(bn * BN + 128 + srow) * K) * 2 + kbsrc;

    // one quarter of a slab's staging
    auto STG = [&](int t, int part) {
        const size_t ko = (size_t)t << 6;               // t * 32k * 2B
        char* d = lds + ((t & 3) * SLOTB) + (wave << 10);
        if (part == 0)      ASYNC16(gA0 + ko, d);
        else if (part == 1) ASYNC16(gA1 + ko, d + 8192);
        else if (part == 2) ASYNC16(gB0 + ko, d + ABYT);
        else                ASYNC16(gB1 + ko, d + ABYT + 8192);
    };

    // fragment read bases (same XOR on read address)
    const int kx = ((lane >> 4) ^ ((lane >> 1) & 3)) << 4;
    const char* pa = lds + (size_t)(wr * 128 + (lane & 15)) * 64 + kx;
    const char* pb = lds + ABYT + (size_t)(wc * 64 + (lane & 15)) * 64 + kx;

    f32x4 acc[8][4] = {};
    bf16x8 aX[8], bX[4], aY[8], bY[4];

#define RD_B(DST, i) DST[i] = *(const bf16x8*)(pb + bon + (i) * 1024)
#define RD_A(DST, i) DST[i] = *(const bf16x8*)(pa + bon + (i) * 1024)
#define MROW(CA, CB, m)                                                       \
    acc[m][0] = MFMA(CA[m], CB[0], acc[m][0]);                                \
    acc[m][1] = MFMA(CA[m], CB[1], acc[m][1]);                                \
    acc[m][2] = MFMA(CA[m], CB[2], acc[m][2]);                                \
    acc[m][3] = MFMA(CA[m], CB[3], acc[m][3]);

    // slab t (R13-verified): compute (CA,CB); weave next-slab reads into
    // (NA,NB); stage quarters of slab t+3 after MROWs 0,1,2,3.
#define SLAB(CA, CB, NA, NB, t, DO_STAGE, DO_NEXT, VMSTMT)                    \
    {                                                                         \
        const int bon = (((t) + 1) & 3) * SLOTB;                              \
        __builtin_amdgcn_s_setprio(1);                                        \
        MROW(CA, CB, 0)                                                       \
        if (DO_NEXT) { RD_B(NB, 0); RD_B(NB, 1); }                            \
        if (DO_STAGE) STG((t) + 3, 0);                                        \
        MROW(CA, CB, 1)                                                       \
        if (DO_NEXT) { RD_B(NB, 2); RD_B(NB, 3); }                            \
        if (DO_STAGE) STG((t) + 3, 1);                                        \
        MROW(CA, CB, 2)                                                       \
        if (DO_NEXT) { RD_A(NA, 0); RD_A(NA, 1); }                            \
        if (DO_STAGE) STG((t) + 3, 2);                                        \
        MROW(CA, CB, 3)                                                       \
        if (DO_NEXT) { RD_A(NA, 2); RD_A(NA, 3); }                            \
        if (DO_STAGE) STG((t) + 3, 3);                                        \
        MROW(CA, CB, 4)                                                       \
        if (DO_NEXT) { RD_A(NA, 4); RD_A(NA, 5); }                            \
        MROW(CA, CB, 5)                                                       \
        if (DO_NEXT) { RD_A(NA, 6); RD_A(NA, 7); }                            \
        MROW(CA, CB, 6)                                                       \
        MROW(CA, CB, 7)                                                       \
        __builtin_amdgcn_s_setprio(0);                                        \
        VMSTMT;                                                               \
        BAR();                                                                \
    }

    const int NT = K >> 5;                   // 128 slabs of 32 k

    // prologue: stage 0,1,2; vmcnt(4) confirms tiles 0 AND 1 (sealed by the
    // barrier for all waves); then load slab-0 fragments into set X.
    STG(0, 0); STG(0, 1); STG(0, 2); STG(0, 3);
    STG(1, 0); STG(1, 1); STG(1, 2); STG(1, 3);
    STG(2, 0); STG(2, 1); STG(2, 2); STG(2, 3);
    VMCNT(4);
    BAR();
    {
        const int bon = 0;
#pragma unroll
        for (int n = 0; n < 4; ++n) RD_B(bX, n);
#pragma unroll
        for (int m = 0; m < 8; ++m) RD_A(aX, m);
    }

    // steady: end-of-slab vmcnt(4) leaves only tile t+3 outstanding ->
    // confirms t+1 (next compute) and t+2 (next slab's woven prefetch).
    for (int t = 0; t < NT - 4; t += 2) {
        SLAB(aX, bX, aY, bY, t,     true, true, VMCNT(4))
        SLAB(aY, bY, aX, bX, t + 1, true, true, VMCNT(4))
    }
    SLAB(aX, bX, aY, bY, NT - 4, true,  true,  VMCNT(4))   // stages NT-1; confirms NT-3,NT-2
    SLAB(aY, bY, aX, bX, NT - 3, false, true,  VMCNT(0))   // confirms NT-1
    SLAB(aX, bX, aY, bY, NT - 2, false, true,  (void)0)
    SLAB(aY, bY, aX, bX, NT - 1, false, false, (void)0)

    // ---- epilogue: C/D layout row=(lane>>4)*4+i, col=lane&15 ----
    const int r0 = bm * BM + wr * 128 + ((lane >> 4) << 2);
    const int c0 = bn * BN + wc * 64 + (lane & 15);
    float bv[4];
#pragma unroll
    for (int n = 0; n < 4; ++n) bv[n] = bias[c0 + n * 16];
#pragma unroll
    for (int m = 0; m < 8; ++m)
#pragma unroll
        for (int n = 0; n < 4; ++n)
#pragma unroll
            for (int i = 0; i < 4; ++i)
                C[(size_t)(r0 + (m << 4) + i) * N + (c0 + (n << 4))] = acc[m][n][i] + bv[n];
}

extern "C" void kernel_launch(void* const* d_in, const int* in_sizes, int n_in,
                              void* d_out, int out_size, void* d_ws, size_t ws_size,
                              hipStream_t stream) {
    const float* x    = (const float*)d_in[0];   // [B,S,K] f32
    const float* w    = (const float*)d_in[1];   // [N,K]   f32
    const float* bias = (const float*)d_in[2];   // [N]     f32
    const float* ss   = (const float*)d_in[3];   // [K/128, N] f32
    float* out        = (float*)d_out;           // [B,S,N] f32

    const int N = in_sizes[2];            // 4096
    const int K = in_sizes[1] / N;        // 4096
    const int M = in_sizes[0] / K;        // 8192

    u16* xb = (u16*)d_ws;                        // [M][K] bf16
    u16* wb = xb + (size_t)M * K;                // [N][K] bf16

    int n8x = (M * K) >> 3;
    int n8w = (N * K) >> 3;
    int tot = n8x + n8w;
    prep_bf16<<<(tot + 255) / 256, 256, 0, stream>>>(x, w, ss, xb, wb, n8x, n8w, N, K);

    (void)hipFuncSetAttribute((const void*)gemm_bf16_bt_256,
                              hipFuncAttributeMaxDynamicSharedMemorySize, LDSB);
    dim3 grid((M / BM) * (N / BN));              // 32*16 = 512, %8 == 0
    gemm_bf16_bt_256<<<grid, 512, LDSB, stream>>>(xb, wb, bias, out, M, N, K);
}